// Round 1
// baseline (831.136 us; speedup 1.0000x reference)
//
#include <hip/hip_runtime.h>
#include <cstdint>
#include <cstddef>

#define T_TOK 512
#define H_DIM 2048
#define E_NUM 32
#define K_TOP 4
#define F_DIM 1024
#define NZ_DIM 16
#define ZH_DIM 512
#define PK 40   // padded K stride (bf16 elems) for LDS tiles: 80B rows, 16B-aligned frags

typedef __attribute__((ext_vector_type(8))) short bf16x8;
typedef __attribute__((ext_vector_type(4))) float f32x4;
typedef __attribute__((ext_vector_type(4))) unsigned short us4;
typedef __attribute__((ext_vector_type(8))) unsigned short us8;

__device__ __forceinline__ unsigned short f2bf(float f) {
  union { float f; unsigned int u; } c; c.f = f;
  unsigned int u = c.u;
  return (unsigned short)((u + 0x7fffu + ((u >> 16) & 1u)) >> 16);  // RNE
}

__device__ __forceinline__ float silu_f(float v) { return v / (1.f + __expf(-v)); }

// ---------------------------------------------------------------------------
// zh = silu(x @ z_w1^T + z_b1)   [512, 512], fp32 (selection-critical)
// grid (16,16), block 256, 32x32 tile, 2x2 per thread
// ---------------------------------------------------------------------------
__global__ __launch_bounds__(256) void zh_gemm_kernel(
    const float* __restrict__ x, const float* __restrict__ z_w1,
    const float* __restrict__ z_b1, float* __restrict__ zh)
{
  __shared__ float xs[32][33];
  __shared__ float ws[32][33];
  const int m0 = blockIdx.x * 32, n0 = blockIdx.y * 32;
  const int tid = threadIdx.x;
  const int tm = tid >> 4, tn = tid & 15;
  const int r = tid >> 3, c4 = (tid & 7) << 2;
  float a00 = 0.f, a01 = 0.f, a10 = 0.f, a11 = 0.f;
  for (int k0 = 0; k0 < H_DIM; k0 += 32) {
    float4 xv = *(const float4*)(x + (size_t)(m0 + r) * H_DIM + k0 + c4);
    xs[r][c4 + 0] = xv.x; xs[r][c4 + 1] = xv.y; xs[r][c4 + 2] = xv.z; xs[r][c4 + 3] = xv.w;
    float4 wv = *(const float4*)(z_w1 + (size_t)(n0 + r) * H_DIM + k0 + c4);
    ws[r][c4 + 0] = wv.x; ws[r][c4 + 1] = wv.y; ws[r][c4 + 2] = wv.z; ws[r][c4 + 3] = wv.w;
    __syncthreads();
    #pragma unroll
    for (int k = 0; k < 32; k++) {
      float x0 = xs[tm * 2][k], x1 = xs[tm * 2 + 1][k];
      float w0 = ws[tn * 2][k], w1 = ws[tn * 2 + 1][k];
      a00 += x0 * w0; a01 += x0 * w1; a10 += x1 * w0; a11 += x1 * w1;
    }
    __syncthreads();
  }
  const float b0 = z_b1[n0 + tn * 2], b1 = z_b1[n0 + tn * 2 + 1];
  float* o0 = zh + (size_t)(m0 + tm * 2) * ZH_DIM + n0 + tn * 2;
  float* o1 = o0 + ZH_DIM;
  o0[0] = silu_f(a00 + b0); o0[1] = silu_f(a01 + b1);
  o1[0] = silu_f(a10 + b0); o1[1] = silu_f(a11 + b1);
}

// ---------------------------------------------------------------------------
// Routing: per-token block. fp32 gate logits + z-router + gumbel argmax +
// softmax + top-4; emits compact per-expert assignment lists via atomics.
// ---------------------------------------------------------------------------
__global__ __launch_bounds__(256) void routing_kernel(
    const float* __restrict__ x, const float* __restrict__ u,
    const float* __restrict__ gate_w, const float* __restrict__ zh,
    const float* __restrict__ z_w2, const float* __restrict__ z_b2,
    const float* __restrict__ Umat, int* __restrict__ cnt,
    int* __restrict__ a_tok, float* __restrict__ a_wgt, int* __restrict__ a_slot)
{
  const int t = blockIdx.x;
  const int tid = threadIdx.x;
  __shared__ float xs[H_DIM];
  __shared__ float red[256];
  __shared__ float zl[NZ_DIM];
  __shared__ float lg[E_NUM];
  __shared__ float prob[E_NUM];
  __shared__ int zi_s;
  __shared__ float mx_s;

  for (int i = tid; i < H_DIM / 4; i += 256)
    ((float4*)xs)[i] = ((const float4*)(x + (size_t)t * H_DIM))[i];

  // z_logits partials: j = tid&15 (output), part = tid>>4 (16 chunks of 32)
  {
    const int j = tid & 15, part = tid >> 4;
    const float* zrow = zh + (size_t)t * ZH_DIM + part * 32;
    const float* wrow = z_w2 + (size_t)j * ZH_DIM + part * 32;
    float s = 0.f;
    #pragma unroll
    for (int i = 0; i < 32; i++) s += zrow[i] * wrow[i];
    red[tid] = s;
  }
  __syncthreads();   // covers xs load + z partials
  if (tid < NZ_DIM) {
    float acc = z_b2[tid];
    #pragma unroll
    for (int p = 0; p < 16; p++) acc += red[p * 16 + tid];
    float uu = u[(size_t)t * NZ_DIM + tid];
    zl[tid] = acc - logf(-logf(uu));   // gumbel, TAU=1
  }
  __syncthreads();

  // router logits partials: e = tid&31, part = tid>>5 (8 chunks of 256)
  {
    const int ee = tid & 31, part = tid >> 5;
    const float* grow = gate_w + (size_t)ee * H_DIM + part * 256;
    const float* xp = xs + part * 256;
    float s = 0.f;
    for (int i = 0; i < 256; i++) s += xp[i] * grow[i];
    red[tid] = s;
  }
  __syncthreads();
  if (tid == 0) {
    int zi = 0; float best = zl[0];
    for (int j = 1; j < NZ_DIM; j++) if (zl[j] > best) { best = zl[j]; zi = j; }
    zi_s = zi;
  }
  __syncthreads();
  if (tid < E_NUM) {
    float acc = 0.f;
    #pragma unroll
    for (int p = 0; p < 8; p++) acc += red[p * 32 + tid];
    lg[tid] = acc + Umat[(size_t)zi_s * E_NUM + tid];
  }
  __syncthreads();
  if (tid == 0) {
    float mx = lg[0];
    for (int i = 1; i < E_NUM; i++) mx = fmaxf(mx, lg[i]);
    mx_s = mx;
  }
  __syncthreads();
  if (tid < E_NUM) prob[tid] = expf(lg[tid] - mx_s);
  __syncthreads();
  if (tid == 0) {
    float sum = 0.f;
    for (int i = 0; i < E_NUM; i++) sum += prob[i];
    const float inv = 1.f / sum;
    unsigned int used = 0;
    for (int k = 0; k < K_TOP; k++) {
      int be = 0; float bv = -1.f;
      for (int i = 0; i < E_NUM; i++)
        if (!((used >> i) & 1u) && prob[i] > bv) { bv = prob[i]; be = i; }
      used |= 1u << be;
      const int pos = atomicAdd(&cnt[be], 1);
      a_tok[be * T_TOK + pos]  = t;
      a_wgt[be * T_TOK + pos]  = bv * inv;
      a_slot[be * T_TOK + pos] = t * K_TOP + k;
    }
  }
}

// ---------------------------------------------------------------------------
// GEMM1: per (expert, f-tile 64, m-tile 128): gp/up via bf16 MFMA 16x16x32,
// epilogue act = silu(gp)*up*w -> bf16 act[slot][f]
// ---------------------------------------------------------------------------
__global__ __launch_bounds__(256) void expert_gemm1(
    const float* __restrict__ x, const float* __restrict__ Wg,
    const float* __restrict__ Wu, const int* __restrict__ cnt,
    const int* __restrict__ a_tok, const float* __restrict__ a_wgt,
    const int* __restrict__ a_slot, unsigned short* __restrict__ act)
{
  const int e = blockIdx.y;
  const int f0 = blockIdx.x * 64;
  const int m_base = blockIdx.z * 128;
  const int n_e = cnt[e];
  if (m_base >= n_e) return;
  const int rows = min(128, n_e - m_base);

  __shared__ unsigned short x_lds[128 * PK];   // [m][k]
  __shared__ unsigned short wg_lds[64 * PK];   // [f][k]  (transposed: K-contig)
  __shared__ unsigned short wu_lds[64 * PK];
  __shared__ int   tok_s[128];
  __shared__ float wgt_s[128];
  __shared__ int   slot_s[128];

  const int tid = threadIdx.x;
  if (tid < 128) {
    int tk = 0, sl = 0; float w = 0.f;
    if (tid < rows) {
      tk = a_tok[e * T_TOK + m_base + tid];
      w  = a_wgt[e * T_TOK + m_base + tid];
      sl = a_slot[e * T_TOK + m_base + tid];
    }
    tok_s[tid] = tk; wgt_s[tid] = w; slot_s[tid] = sl;
  }
  __syncthreads();

  const int wave = tid >> 6, lane = tid & 63;
  const int lm = lane & 15, quad = lane >> 4;
  f32x4 accg[2][4], accu[2][4];
  const f32x4 zero4 = {0.f, 0.f, 0.f, 0.f};
  #pragma unroll
  for (int i = 0; i < 2; i++)
    #pragma unroll
    for (int j = 0; j < 4; j++) { accg[i][j] = zero4; accu[i][j] = zero4; }

  const size_t wbase = (size_t)e * H_DIM * F_DIM;
  const int xr = tid >> 3, xc = (tid & 7) << 2;
  const int wk = tid >> 4, wf = (tid & 15) << 2;

  for (int k0 = 0; k0 < H_DIM; k0 += 32) {
    #pragma unroll
    for (int i = 0; i < 4; i++) {
      const int m = i * 32 + xr;
      const float4 v = *(const float4*)(x + (size_t)tok_s[m] * H_DIM + k0 + xc);
      us4 pv; pv[0] = f2bf(v.x); pv[1] = f2bf(v.y); pv[2] = f2bf(v.z); pv[3] = f2bf(v.w);
      *(us4*)(x_lds + m * PK + xc) = pv;
    }
    #pragma unroll
    for (int p = 0; p < 2; p++) {
      const int kk = p * 16 + wk;
      const float4 g = *(const float4*)(Wg + wbase + (size_t)(k0 + kk) * F_DIM + f0 + wf);
      wg_lds[(wf + 0) * PK + kk] = f2bf(g.x);
      wg_lds[(wf + 1) * PK + kk] = f2bf(g.y);
      wg_lds[(wf + 2) * PK + kk] = f2bf(g.z);
      wg_lds[(wf + 3) * PK + kk] = f2bf(g.w);
      const float4 uv = *(const float4*)(Wu + wbase + (size_t)(k0 + kk) * F_DIM + f0 + wf);
      wu_lds[(wf + 0) * PK + kk] = f2bf(uv.x);
      wu_lds[(wf + 1) * PK + kk] = f2bf(uv.y);
      wu_lds[(wf + 2) * PK + kk] = f2bf(uv.z);
      wu_lds[(wf + 3) * PK + kk] = f2bf(uv.w);
    }
    __syncthreads();
    #pragma unroll
    for (int ms = 0; ms < 2; ms++) {
      const bf16x8 a = *(const bf16x8*)(x_lds + (wave * 32 + ms * 16 + lm) * PK + quad * 8);
      #pragma unroll
      for (int ns = 0; ns < 4; ns++) {
        const bf16x8 bg = *(const bf16x8*)(wg_lds + (ns * 16 + lm) * PK + quad * 8);
        accg[ms][ns] = __builtin_amdgcn_mfma_f32_16x16x32_bf16(a, bg, accg[ms][ns], 0, 0, 0);
        const bf16x8 bu = *(const bf16x8*)(wu_lds + (ns * 16 + lm) * PK + quad * 8);
        accu[ms][ns] = __builtin_amdgcn_mfma_f32_16x16x32_bf16(a, bu, accu[ms][ns], 0, 0, 0);
      }
    }
    __syncthreads();
  }
  // epilogue: D layout col = lane&15, row = quad*4 + r  (guide-verified)
  #pragma unroll
  for (int ms = 0; ms < 2; ms++) {
    #pragma unroll
    for (int r = 0; r < 4; r++) {
      const int m = wave * 32 + ms * 16 + quad * 4 + r;
      if (m < rows) {
        const float w = wgt_s[m];
        unsigned short* orow = act + (size_t)slot_s[m] * F_DIM + f0 + lm;
        #pragma unroll
        for (int ns = 0; ns < 4; ns++) {
          const float g = accg[ms][ns][r];
          const float uu = accu[ms][ns][r];
          orow[ns * 16] = f2bf(silu_f(g) * uu * w);
        }
      }
    }
  }
}

// ---------------------------------------------------------------------------
// GEMM2: per (expert, h-tile 64, m-tile 128): out += act @ Wd[e], fp32 atomics
// ---------------------------------------------------------------------------
__global__ __launch_bounds__(256) void expert_gemm2(
    const unsigned short* __restrict__ act, const float* __restrict__ Wd,
    const int* __restrict__ cnt, const int* __restrict__ a_tok,
    const int* __restrict__ a_slot, float* __restrict__ out)
{
  const int e = blockIdx.y;
  const int h0 = blockIdx.x * 64;
  const int m_base = blockIdx.z * 128;
  const int n_e = cnt[e];
  if (m_base >= n_e) return;
  const int rows = min(128, n_e - m_base);

  __shared__ unsigned short a_lds[128 * PK];
  __shared__ unsigned short wd_lds[64 * PK];
  __shared__ int tok_s[128];
  __shared__ int slot_s[128];

  const int tid = threadIdx.x;
  if (tid < 128) {
    int tk = 0, sl = 0;
    if (tid < rows) {
      tk = a_tok[e * T_TOK + m_base + tid];
      sl = a_slot[e * T_TOK + m_base + tid];
    }
    tok_s[tid] = tk; slot_s[tid] = sl;
  }
  __syncthreads();

  const int wave = tid >> 6, lane = tid & 63;
  const int lm = lane & 15, quad = lane >> 4;
  f32x4 acc[2][4];
  const f32x4 zero4 = {0.f, 0.f, 0.f, 0.f};
  #pragma unroll
  for (int i = 0; i < 2; i++)
    #pragma unroll
    for (int j = 0; j < 4; j++) acc[i][j] = zero4;

  const size_t wbase = (size_t)e * F_DIM * H_DIM;
  const int ar = tid >> 2, aq = (tid & 3) << 3;
  const int wk = tid >> 4, wh = (tid & 15) << 2;

  for (int k0 = 0; k0 < F_DIM; k0 += 32) {
    #pragma unroll
    for (int i = 0; i < 2; i++) {
      const int m = i * 64 + ar;
      const us8 v = *(const us8*)(act + (size_t)slot_s[m] * F_DIM + k0 + aq);
      *(us8*)(a_lds + m * PK + aq) = v;
    }
    #pragma unroll
    for (int p = 0; p < 2; p++) {
      const int kk = p * 16 + wk;
      const float4 dv = *(const float4*)(Wd + wbase + (size_t)(k0 + kk) * H_DIM + h0 + wh);
      wd_lds[(wh + 0) * PK + kk] = f2bf(dv.x);
      wd_lds[(wh + 1) * PK + kk] = f2bf(dv.y);
      wd_lds[(wh + 2) * PK + kk] = f2bf(dv.z);
      wd_lds[(wh + 3) * PK + kk] = f2bf(dv.w);
    }
    __syncthreads();
    #pragma unroll
    for (int ms = 0; ms < 2; ms++) {
      const bf16x8 a = *(const bf16x8*)(a_lds + (wave * 32 + ms * 16 + lm) * PK + quad * 8);
      #pragma unroll
      for (int ns = 0; ns < 4; ns++) {
        const bf16x8 b = *(const bf16x8*)(wd_lds + (ns * 16 + lm) * PK + quad * 8);
        acc[ms][ns] = __builtin_amdgcn_mfma_f32_16x16x32_bf16(a, b, acc[ms][ns], 0, 0, 0);
      }
    }
    __syncthreads();
  }
  #pragma unroll
  for (int ms = 0; ms < 2; ms++) {
    #pragma unroll
    for (int r = 0; r < 4; r++) {
      const int m = wave * 32 + ms * 16 + quad * 4 + r;
      if (m < rows) {
        float* orow = out + (size_t)tok_s[m] * H_DIM + h0 + lm;
        #pragma unroll
        for (int ns = 0; ns < 4; ns++) atomicAdd(orow + ns * 16, acc[ms][ns][r]);
      }
    }
  }
}

// ---------------------------------------------------------------------------
extern "C" void kernel_launch(void* const* d_in, const int* in_sizes, int n_in,
                              void* d_out, int out_size, void* d_ws, size_t ws_size,
                              hipStream_t stream)
{
  const float* x      = (const float*)d_in[0];
  const float* u      = (const float*)d_in[1];
  const float* gate_w = (const float*)d_in[2];
  const float* z_w1   = (const float*)d_in[3];
  const float* z_b1   = (const float*)d_in[4];
  const float* z_w2   = (const float*)d_in[5];
  const float* z_b2   = (const float*)d_in[6];
  const float* Umat   = (const float*)d_in[7];
  const float* Wg     = (const float*)d_in[8];
  const float* Wu     = (const float*)d_in[9];
  const float* Wd     = (const float*)d_in[10];
  float* out = (float*)d_out;

  char* ws = (char*)d_ws;
  int*   cnt    = (int*)(ws);                                  // 32 ints
  int*   a_tok  = (int*)(ws + 256);                            // 32*512
  float* a_wgt  = (float*)(ws + 256 + 65536);
  int*   a_slot = (int*)(ws + 256 + 2 * 65536);
  float* zh     = (float*)(ws + 256 + 3 * 65536);              // 512*512 fp32
  unsigned short* act = (unsigned short*)(ws + 256 + 3 * 65536 + 1048576); // 2048*1024 bf16

  hipMemsetAsync(cnt, 0, E_NUM * sizeof(int), stream);
  hipMemsetAsync(out, 0, (size_t)T_TOK * H_DIM * sizeof(float), stream);

  zh_gemm_kernel<<<dim3(16, 16), 256, 0, stream>>>(x, z_w1, z_b1, zh);
  routing_kernel<<<dim3(T_TOK), 256, 0, stream>>>(x, u, gate_w, zh, z_w2, z_b2, Umat,
                                                  cnt, a_tok, a_wgt, a_slot);
  expert_gemm1<<<dim3(F_DIM / 64, E_NUM, 4), 256, 0, stream>>>(
      x, Wg, Wu, cnt, a_tok, a_wgt, a_slot, act);
  expert_gemm2<<<dim3(H_DIM / 64, E_NUM, 4), 256, 0, stream>>>(
      act, Wd, cnt, a_tok, a_slot, out);
}